// Round 4
// baseline (698.862 us; speedup 1.0000x reference)
//
#include <hip/hip_runtime.h>

#define N    1024
#define BSZ  32
#define PS   480     // per-sample param stride: 169 W13 + 147 w1 + 147 w2 + 9 kA
#define HID  100

// ---------------------------------------------------------------------------
// Kernel 1: per-sample MLPs + composed 13x13 kernel
// ---------------------------------------------------------------------------
__global__ __launch_bounds__(256) void prep_kernel(
    const float* __restrict__ kernelA,
    const float* __restrict__ fc1_w1, const float* __restrict__ fc1_b1,
    const float* __restrict__ fc1_w2, const float* __restrict__ fc1_b2,
    const float* __restrict__ fc2_w1, const float* __restrict__ fc2_b1,
    const float* __restrict__ fc2_w2, const float* __restrict__ fc2_b2,
    float* __restrict__ params)
{
    int b = blockIdx.x, t = threadIdx.x;
    __shared__ float w[9], h1[HID], h2[HID], w1[147], w2[147];
    if (t < 9) w[t] = kernelA[b * 9 + t];
    __syncthreads();
    if (t < HID) {
        float s1 = fc1_b1[t], s2 = fc2_b1[t];
        #pragma unroll
        for (int i = 0; i < 9; ++i) {
            s1 = fmaf(w[i], fc1_w1[i * HID + t], s1);
            s2 = fmaf(w[i], fc2_w1[i * HID + t], s2);
        }
        h1[t] = fmaxf(s1, 0.f);
        h2[t] = fmaxf(s2, 0.f);
    }
    __syncthreads();
    if (t < 147) {
        float s1 = fc1_b2[t], s2 = fc2_b2[t];
        for (int i = 0; i < HID; ++i) {
            s1 = fmaf(h1[i], fc1_w2[i * 147 + t], s1);
            s2 = fmaf(h2[i], fc2_w2[i * 147 + t], s2);
        }
        w1[t] = s1;
        w2[t] = s2;
    }
    __syncthreads();
    float* P = params + b * PS;
    if (t < 169) {   // W13[ey][ex] = sum_m sum_{d1+d2=e} w1[m,d1] * w2[m,d2]
        int ey = t / 13, ex = t % 13;
        float s = 0.f;
        for (int m = 0; m < 3; ++m)
            for (int d1y = 0; d1y < 7; ++d1y) {
                int d2y = ey - d1y;
                if (d2y < 0 || d2y > 6) continue;
                for (int d1x = 0; d1x < 7; ++d1x) {
                    int d2x = ex - d1x;
                    if (d2x < 0 || d2x > 6) continue;
                    s = fmaf(w1[m * 49 + d1y * 7 + d1x],
                             w2[m * 49 + d2y * 7 + d2x], s);
                }
            }
        P[t] = s;
    }
    if (t < 147) { P[169 + t] = w1[t]; P[316 + t] = w2[t]; }
    if (t < 9)   P[463 + t] = w[t];
}

// ---------------------------------------------------------------------------
// Kernel 2: interior — composed 13x13 conv over r, ALL pixels (border pixels
// get the composed value; corr_kernel subtracts the exterior-tmp terms).
// Single in-place LDS buffer (26.5 KB -> 6 blocks/CU). 4x4 outputs/thread.
// F quads prefetched before the phase-1 barrier; epilogue X prefetched before
// phase-4 compute.
// ---------------------------------------------------------------------------
#define TR 32
#define TC 128
#define XR 46      // x rows (TR+14)
#define XC 144     // x row pitch (TC+14 rounded up, b128-aligned rows)
#define RRW 44     // r rows (TR+12)
#define RC 140     // r row pitch (TC+12, 560B = 16B-aligned rows)
#define NQ 1540    // r quads: 44 * 35

__device__ __forceinline__ void conv_row(const float* win, const float* __restrict__ P,
                                         int ky, float* accRow)
{
    #pragma unroll
    for (int c = 0; c < 13; ++c) {
        float tv = P[ky * 13 + c];          // block-uniform -> scalar load
        #pragma unroll
        for (int j = 0; j < 4; ++j)
            accRow[j] = fmaf(win[c + j], tv, accRow[j]);
    }
}

__global__ __launch_bounds__(256, 6) void main_kernel(
    const float* __restrict__ X, const float* __restrict__ F,
    const float* __restrict__ params, float* __restrict__ out)
{
    __shared__ __align__(16) float buf[XR * XC];   // 26496 B
    const int t  = threadIdx.x;
    const int b  = blockIdx.z;
    const int y0 = blockIdx.y * TR;
    const int x0 = blockIdx.x * TC;
    const float* P  = params + b * PS;
    const float* Xb = X + (size_t)b * N * N;
    const float* Fb = F + (size_t)b * N * N;
    float*       Ob = out + (size_t)b * N * N;

    // ---- phase 1: stage x tile (halo 7), zero-extended
    for (int idx = t; idx < XR * XC; idx += 256) {
        int i = idx / XC, j = idx - i * XC;
        int gy = y0 - 7 + i, gx = x0 - 7 + j;
        buf[idx] = (gy >= 0 && gy < N && gx >= 0 && gx < N) ? Xb[gy * N + gx] : 0.f;
    }

    // ---- prefetch F quads (overlaps phase-1 barrier + LDS writes).
    // quad base gxb = x0-6+4q is 8B-aligned -> two float2 loads.
    float fq[7][4];
    #pragma unroll
    for (int k = 0; k < 7; ++k) {
        int idx = t + k * 256;
        fq[k][0] = fq[k][1] = fq[k][2] = fq[k][3] = 0.f;
        if (idx < NQ) {
            int i = idx / 35;
            int j = (idx - i * 35) * 4;
            int gy = y0 - 6 + i, gxb = x0 - 6 + j;
            if (gy >= 0 && gy < N) {
                if (gxb >= 0 && gxb + 3 < N) {
                    float2 a = *reinterpret_cast<const float2*>(&Fb[gy * N + gxb]);
                    float2 c = *reinterpret_cast<const float2*>(&Fb[gy * N + gxb + 2]);
                    fq[k][0] = a.x; fq[k][1] = a.y; fq[k][2] = c.x; fq[k][3] = c.y;
                } else {
                    #pragma unroll
                    for (int c = 0; c < 4; ++c) {
                        int gx = gxb + c;
                        if (gx >= 0 && gx < N) fq[k][c] = Fb[gy * N + gx];
                    }
                }
            }
        }
    }
    __syncthreads();

    float ka[9];
    #pragma unroll
    for (int i = 0; i < 9; ++i) ka[i] = P[463 + i];  // uniform -> SGPR

    // ---- phase 2: r = f - corr3x3(x,kA) into registers, quad-granular
    float rq[7][4];
    #pragma unroll
    for (int k = 0; k < 7; ++k) {
        int idx = t + k * 256;
        if (idx < NQ) {
            int i = idx / 35;
            int j = (idx - i * 35) * 4;
            const float* xr = &buf[i * XC + j];
            float s[4] = {0.f, 0.f, 0.f, 0.f};
            #pragma unroll
            for (int dy = 0; dy < 3; ++dy) {
                float w8[8];
                float4 v0 = *reinterpret_cast<const float4*>(xr + dy * XC);
                float4 v1 = *reinterpret_cast<const float4*>(xr + dy * XC + 4);
                w8[0] = v0.x; w8[1] = v0.y; w8[2] = v0.z; w8[3] = v0.w;
                w8[4] = v1.x; w8[5] = v1.y; w8[6] = v1.z; w8[7] = v1.w;
                #pragma unroll
                for (int dx = 0; dx < 3; ++dx)
                    #pragma unroll
                    for (int c = 0; c < 4; ++c)
                        s[c] = fmaf(ka[dy * 3 + dx], w8[dx + c], s[c]);
            }
            int gy = y0 - 6 + i, gxb = x0 - 6 + j;
            #pragma unroll
            for (int c = 0; c < 4; ++c) {
                int gx = gxb + c;
                rq[k][c] = (gy >= 0 && gy < N && gx >= 0 && gx < N)
                           ? (fq[k][c] - s[c]) : 0.f;
            }
        }
    }
    __syncthreads();

    // ---- phase 3: write r back into buf (RC pitch), b128, contiguous lanes
    #pragma unroll
    for (int k = 0; k < 7; ++k) {
        int idx = t + k * 256;
        if (idx < NQ) {
            int i = idx / 35;
            int j = (idx - i * 35) * 4;
            float4 v; v.x = rq[k][0]; v.y = rq[k][1]; v.z = rq[k][2]; v.w = rq[k][3];
            *reinterpret_cast<float4*>(&buf[i * RC + j]) = v;
        }
    }
    __syncthreads();

    // ---- phase 4: 13x13 composed conv, 4x4 per thread
    const int tx4 = (t & 31) * 4;   // col offset (0..124)
    const int ty4 = (t >> 5) * 4;   // row offset (0..28)
    const float* rbase = &buf[ty4 * RC + tx4];

    // prefetch epilogue x quads (latency hidden behind 2704 FMAs)
    float4 xq[4];
    #pragma unroll
    for (int i = 0; i < 4; ++i)
        xq[i] = *reinterpret_cast<const float4*>(&Xb[(y0 + ty4 + i) * N + (x0 + tx4)]);

    float acc[4][4] = {{0.f,0.f,0.f,0.f},{0.f,0.f,0.f,0.f},
                       {0.f,0.f,0.f,0.f},{0.f,0.f,0.f,0.f}};
    float win[16];

    #define LOAD_WIN(rr)                                                     \
        { float4 v0 = *reinterpret_cast<const float4*>(rbase + (rr) * RC);   \
          float4 v1 = *reinterpret_cast<const float4*>(rbase + (rr) * RC + 4);\
          float4 v2 = *reinterpret_cast<const float4*>(rbase + (rr) * RC + 8);\
          float4 v3 = *reinterpret_cast<const float4*>(rbase + (rr) * RC + 12);\
          win[0]=v0.x; win[1]=v0.y; win[2]=v0.z; win[3]=v0.w;                \
          win[4]=v1.x; win[5]=v1.y; win[6]=v1.z; win[7]=v1.w;                \
          win[8]=v2.x; win[9]=v2.y; win[10]=v2.z; win[11]=v2.w;              \
          win[12]=v3.x; win[13]=v3.y; win[14]=v3.z; win[15]=v3.w; }

    LOAD_WIN(0);
    conv_row(win, P, 0, acc[0]);
    LOAD_WIN(1);
    conv_row(win, P, 1, acc[0]);
    conv_row(win, P, 0, acc[1]);
    LOAD_WIN(2);
    conv_row(win, P, 2, acc[0]);
    conv_row(win, P, 1, acc[1]);
    conv_row(win, P, 0, acc[2]);

    for (int rr = 3; rr <= 12; ++rr) {
        LOAD_WIN(rr);
        #pragma unroll
        for (int i = 0; i < 4; ++i)
            conv_row(win, P, rr - i, acc[i]);
    }

    LOAD_WIN(13);
    conv_row(win, P, 12, acc[1]);
    conv_row(win, P, 11, acc[2]);
    conv_row(win, P, 10, acc[3]);
    LOAD_WIN(14);
    conv_row(win, P, 12, acc[2]);
    conv_row(win, P, 11, acc[3]);
    LOAD_WIN(15);
    conv_row(win, P, 12, acc[3]);

    // ---- epilogue: out = x + G2
    #pragma unroll
    for (int i = 0; i < 4; ++i) {
        float4 o;
        o.x = xq[i].x + acc[i][0]; o.y = xq[i].y + acc[i][1];
        o.z = xq[i].z + acc[i][2]; o.w = xq[i].w + acc[i][3];
        *reinterpret_cast<float4*>(&Ob[(y0 + ty4 + i) * N + (x0 + tx4)]) = o;
    }
}

// ---------------------------------------------------------------------------
// Kernel 3: border CORRECTION. The composed conv (written everywhere by
// main_kernel) differs from the reference only by contributions through tmp
// positions OUTSIDE the image (the reference clips tmp to [0,N)^2). Compute
// the 3-px exterior tmp ring and subtract sum(w2 * tmp_ext) from pixels
// within 3 of the edge. Bands are disjoint (top/bottom own the corner
// exteriors); corners get two bands' corrections via atomicAdd.
//   edge: 0 top (across<0), 1 bottom (across>=N), 2 left, 3 right
//   across = perpendicular-to-edge coord, along = edge direction.
// ---------------------------------------------------------------------------
#define CSEG   256
#define TEX_U  262     // tmp along: [u0-3, u0+258]
#define TPITCH 264
#define REX_U  268     // r along: [u0-6, u0+261]
#define RPITCH 272
#define XEX_U  270     // x along: [u0-7, u0+262]
#define XPITCH 272

__global__ __launch_bounds__(256) void corr_kernel(
    const float* __restrict__ X, const float* __restrict__ F,
    const float* __restrict__ params, float* __restrict__ out)
{
    __shared__ float xs[5 * XPITCH];
    __shared__ float rs[3 * RPITCH];
    __shared__ float tmp[9 * TPITCH];
    __shared__ float sw1[147], sw2[147];

    const int  t    = threadIdx.x;
    const int  b    = blockIdx.z;
    const int  edge = blockIdx.y;
    const int  u0   = blockIdx.x * CSEG;
    const bool vert = (edge >= 2);
    const bool hi   = (edge & 1);
    const int  ar0  = hi ? (N - 3) : 0;   // r across origin (3 rows staged)

    const float* P  = params + b * PS;
    const float* Xb = X + (size_t)b * N * N;
    const float* Fb = F + (size_t)b * N * N;
    float*       Ob = out + (size_t)b * N * N;

    if (t < 147) { sw1[t] = P[169 + t]; sw2[t] = P[316 + t]; }
    float ka[9];
    #pragma unroll
    for (int i = 0; i < 9; ++i) ka[i] = P[463 + i];

    // stage x: across slots 0..4 <-> global (ar0-1)+ax, along [u0-7, u0+262]
    for (int idx = t; idx < 5 * XEX_U; idx += 256) {
        int ax = idx / XEX_U, u = idx - ax * XEX_U;
        int ga = (ar0 - 1) + ax, gl = u0 - 7 + u;
        int gy = vert ? gl : ga, gx = vert ? ga : gl;
        xs[ax * XPITCH + u] =
            (gy >= 0 && gy < N && gx >= 0 && gx < N) ? Xb[gy * N + gx] : 0.f;
    }
    __syncthreads();

    // r = f - corr3x3(x,kA): 3 across rows (the in-image rows the exterior
    // tmp can reach), along [u0-6, u0+261], zero where outside image
    for (int idx = t; idx < 3 * REX_U; idx += 256) {
        int ar = idx / REX_U, u = idx - ar * REX_U;
        int ga = ar0 + ar, gl = u0 - 6 + u;
        int gy = vert ? gl : ga, gx = vert ? ga : gl;
        float v = 0.f;
        if (gy >= 0 && gy < N && gx >= 0 && gx < N) {
            float sc = 0.f;
            #pragma unroll
            for (int da = 0; da < 3; ++da)
                #pragma unroll
                for (int dl = 0; dl < 3; ++dl)
                    sc = fmaf(ka[vert ? (dl * 3 + da) : (da * 3 + dl)],
                              xs[(ar + da) * XPITCH + (u + dl)], sc);
            v = Fb[gy * N + gx] - sc;
        }
        rs[ar * RPITCH + u] = v;
    }
    __syncthreads();

    // tmp_ext[m][ai][u]: band across = hi ? N+ai : ai-3; band along = u0-3+u.
    // Vertical bands only exist for along in [0,N) -> zero otherwise.
    for (int idx = t; idx < 9 * TEX_U; idx += 256) {
        int m   = idx / (3 * TEX_U);
        int rem = idx - m * (3 * TEX_U);
        int ai = rem / TEX_U, u = rem - ai * TEX_U;
        int bl = u0 - 3 + u;
        float sc = 0.f;
        if (!vert || (bl >= 0 && bl < N)) {
            #pragma unroll
            for (int da = 0; da < 7; ++da) {
                int ri = hi ? (ai + da) : (ai - 6 + da);   // r across slot
                if (ri < 0 || ri > 2) continue;            // outside image -> 0
                #pragma unroll
                for (int dl = 0; dl < 7; ++dl)
                    sc = fmaf(sw1[m * 49 + (vert ? (dl * 7 + da) : (da * 7 + dl))],
                              rs[ri * RPITCH + (u + dl)], sc);
            }
        }
        tmp[(m * 3 + ai) * TPITCH + u] = sc;
    }
    __syncthreads();

    // corrections: 3 across x CSEG along; subtract sum(w2 * tmp_ext)
    for (int idx = t; idx < 3 * CSEG; idx += 256) {
        int oy = idx / CSEG, u = idx - oy * CSEG;
        int ol = u0 + u;                       // along global (< N by grid)
        int oa = hi ? (N - 3 + oy) : oy;       // across global
        float C = 0.f;
        #pragma unroll
        for (int m = 0; m < 3; ++m)
            #pragma unroll
            for (int ai = 0; ai < 3; ++ai) {
                int dperp = hi ? (ai - oy + 6) : (ai - oy);  // w2 perp index
                if (dperp < 0 || dperp > 6) continue;
                #pragma unroll
                for (int du = 0; du < 7; ++du)
                    C = fmaf(sw2[m * 49 + (vert ? (du * 7 + dperp)
                                                : (dperp * 7 + du))],
                             tmp[(m * 3 + ai) * TPITCH + (u + du)], C);
            }
        int gy = vert ? ol : oa, gx = vert ? oa : ol;
        atomicAdd(&Ob[gy * N + gx], -C);
    }
}

// ---------------------------------------------------------------------------
extern "C" void kernel_launch(void* const* d_in, const int* in_sizes, int n_in,
                              void* d_out, int out_size, void* d_ws, size_t ws_size,
                              hipStream_t stream)
{
    const float* x    = (const float*)d_in[0];
    const float* f    = (const float*)d_in[1];
    const float* kA   = (const float*)d_in[2];
    const float* f1w1 = (const float*)d_in[3];
    const float* f1b1 = (const float*)d_in[4];
    const float* f1w2 = (const float*)d_in[5];
    const float* f1b2 = (const float*)d_in[6];
    const float* f2w1 = (const float*)d_in[7];
    const float* f2b1 = (const float*)d_in[8];
    const float* f2w2 = (const float*)d_in[9];
    const float* f2b2 = (const float*)d_in[10];
    float* out    = (float*)d_out;
    float* params = (float*)d_ws;   // BSZ * PS floats = 61440 B

    prep_kernel<<<BSZ, 256, 0, stream>>>(kA, f1w1, f1b1, f1w2, f1b2,
                                         f2w1, f2b1, f2w2, f2b2, params);
    main_kernel<<<dim3(N / TC, N / TR, BSZ), 256, 0, stream>>>(x, f, params, out);
    corr_kernel<<<dim3(N / CSEG, 4, BSZ), 256, 0, stream>>>(x, f, params, out);
}